// Round 2
// baseline (271.716 us; speedup 1.0000x reference)
//
#include <hip/hip_runtime.h>
#include <cstdint>

// ---------------------------------------------------------------------------
// Threefry-2x32, 20 rounds — bit-exact match for JAX's threefry2x32_p
// (partitionable path: bits[i] = o0^o1 with x0=0, x1=i, key=(0,42)).
// Verified absmax 0.0 vs reference in R1.
// ---------------------------------------------------------------------------
static __device__ __forceinline__ uint32_t rotl32(uint32_t x, int r) {
  return (x << r) | (x >> (32 - r));
}

static __device__ __forceinline__ void threefry2x32(uint32_t k0, uint32_t k1,
                                                    uint32_t& x0, uint32_t& x1) {
  const uint32_t ks2 = 0x1BD11BDAu ^ k0 ^ k1;
  x0 += k0;
  x1 += k1;
#define TF_R(r)                        \
  x0 += x1;                            \
  x1 = rotl32(x1, (r));                \
  x1 ^= x0;
  TF_R(13) TF_R(15) TF_R(26) TF_R(6)
  x0 += k1;  x1 += ks2 + 1u;
  TF_R(17) TF_R(29) TF_R(16) TF_R(24)
  x0 += ks2; x1 += k0 + 2u;
  TF_R(13) TF_R(15) TF_R(26) TF_R(6)
  x0 += k0;  x1 += k1 + 3u;
  TF_R(17) TF_R(29) TF_R(16) TF_R(24)
  x0 += k1;  x1 += ks2 + 4u;
  TF_R(13) TF_R(15) TF_R(26) TF_R(6)
  x0 += ks2; x1 += k0 + 5u;
#undef TF_R
}

static __device__ __forceinline__ float row_scale(uint32_t v) {
  uint32_t a = 0u, b = v;
  threefry2x32(0u, 42u, a, b);
  const uint32_t bits = a ^ b;
  const float u = __uint_as_float((bits >> 9) | 0x3f800000u) - 1.0f;
  return (u < 0.9f) ? (1.0f / 0.9f) : 0.0f;
}

// One WAVE per token (4 tokens / 256-thread block). Each lane issues 4
// independent float4 loads (4 KB in flight per wave) before any store —
// 4x the memory-level parallelism of the R1 one-load-per-thread version.
// Row layout: 256 float4s; lane L handles float4 indices L, L+64, L+128,
// L+192 — each instruction is a fully-coalesced 1 KB wave access.
__global__ __launch_bounds__(256) void embed_dropout_kernel(
    const int* __restrict__ x, const float4* __restrict__ w4,
    float4* __restrict__ out4) {
  const int wave = threadIdx.x >> 6;
  const int lane = threadIdx.x & 63;
  const int t = (blockIdx.x << 2) + wave;

  // Force token id into an SGPR: threefry runs on the scalar pipe, and the
  // row base becomes wave-uniform (saddr-form global loads).
  const uint32_t v = (uint32_t)__builtin_amdgcn_readfirstlane(x[t]);
  const float scale = row_scale(v);

  const float4* __restrict__ src = w4 + (size_t)v * 256u + lane;
  float4* __restrict__ dst = out4 + (size_t)t * 256u + lane;

  float4 a = src[0];
  float4 b = src[64];
  float4 c = src[128];
  float4 d = src[192];

  a.x *= scale; a.y *= scale; a.z *= scale; a.w *= scale;
  b.x *= scale; b.y *= scale; b.z *= scale; b.w *= scale;
  c.x *= scale; c.y *= scale; c.z *= scale; c.w *= scale;
  d.x *= scale; d.y *= scale; d.z *= scale; d.w *= scale;

  dst[0]   = a;
  dst[64]  = b;
  dst[128] = c;
  dst[192] = d;
}

extern "C" void kernel_launch(void* const* d_in, const int* in_sizes, int n_in,
                              void* d_out, int out_size, void* d_ws, size_t ws_size,
                              hipStream_t stream) {
  const int* x = (const int*)d_in[0];          // [8,2048] token ids (int32)
  const float* w = (const float*)d_in[1];      // [50257,1024] f32
  float* out = (float*)d_out;                  // [8,2048,1024] f32

  const int tokens = in_sizes[0];              // 16384
  const int blocks = tokens >> 2;              // 4 tokens (waves) per block
  embed_dropout_kernel<<<blocks, 256, 0, stream>>>(
      x, (const float4*)w, (float4*)out);
}